// Round 1
// baseline (215.972 us; speedup 1.0000x reference)
//
#include <hip/hip_runtime.h>
#include <hip/hip_bf16.h>
#include <math.h>

#define NTOK 4096
#define DEMB 256
#define NHEAD 4
#define HD 64

typedef short bf16x8 __attribute__((ext_vector_type(8)));
typedef short bf16x4 __attribute__((ext_vector_type(4)));
typedef float f32x4 __attribute__((ext_vector_type(4)));

__device__ __forceinline__ unsigned short f2b(float f) {
  union { float f; unsigned u; } v; v.f = f;
  return (unsigned short)((v.u + 0x7FFFu + ((v.u >> 16) & 1u)) >> 16);
}

// ---- prep 1: transpose+cast the 4 weight matrices to bf16 [out][in] ----
__global__ void wtrans_kernel(const float* wq, const float* wk, const float* wv,
                              const float* wo, unsigned short* wt) {
  int idx = blockIdx.x * 256 + threadIdx.x;  // 4 * 256 * 256
  int m = idx >> 16, rest = idx & 0xFFFF;
  int o = rest >> 8, i = rest & 255;
  const float* w = (m == 0) ? wq : (m == 1) ? wk : (m == 2) ? wv : wo;
  wt[idx] = f2b(w[i * 256 + o]);
}

// ---- prep 2: RoPE cos/sin table [NTOK][32] as float2(cos,sin) ----
__global__ void cs_kernel(float2* cs) {
  int idx = blockIdx.x * 256 + threadIdx.x;  // 4096*32
  int n = idx >> 5, p = idx & 31;
  int j = p & 15;
  float f = powf(10000.0f, -(float)j / 16.0f);
  float ang = ((p < 16) ? (float)(n & 63) : (float)(n >> 6)) * f;
  cs[idx] = make_float2(cosf(ang), sinf(ang));
}

// ---- fused QKV projection + bias + RoPE; z = 0:q 1:k 2:v ----
// outputs: qp/kp bf16 [h][n][d] (q pre-scaled by 0.125*log2e), vt bf16 [h][d][n]
__global__ __launch_bounds__(256) void qkvproj_kernel(
    const float* q, const float* k, const float* v, const unsigned short* wt,
    const float* bq, const float* bk, const float* bv, const float2* cs,
    unsigned short* qp, unsigned short* kp, unsigned short* vt) {
  int which = blockIdx.z;
  int wave = threadIdx.x >> 6, lane = threadIdx.x & 63;
  int col = lane & 15, g = lane >> 4;
  int mbase = blockIdx.x * 64 + wave * 16;
  int nbase = blockIdx.y * 64;
  const float* X = (which == 0) ? q : (which == 1) ? k : v;
  const unsigned short* W = wt + which * 65536;
  const float* bias = (which == 0) ? bq : (which == 1) ? bk : bv;

  f32x4 acc[4] = {};
  const float* ap0 = X + (mbase + col) * 256 + g * 8;
#pragma unroll
  for (int ks = 0; ks < 256; ks += 32) {
    float4 a0 = *(const float4*)(ap0 + ks);
    float4 a1 = *(const float4*)(ap0 + ks + 4);
    bf16x8 af;
    af[0] = (short)f2b(a0.x); af[1] = (short)f2b(a0.y);
    af[2] = (short)f2b(a0.z); af[3] = (short)f2b(a0.w);
    af[4] = (short)f2b(a1.x); af[5] = (short)f2b(a1.y);
    af[6] = (short)f2b(a1.z); af[7] = (short)f2b(a1.w);
#pragma unroll
    for (int nt = 0; nt < 4; ++nt) {
      bf16x8 bf_ = *(const bf16x8*)(W + (nbase + nt * 16 + col) * 256 + ks + g * 8);
      acc[nt] = __builtin_amdgcn_mfma_f32_16x16x32_bf16(af, bf_, acc[nt], 0, 0, 0);
    }
  }

  if (which == 2) {
    // V: bias only, store transposed vt[c][n] with 4 consecutive tokens packed
#pragma unroll
    for (int nt = 0; nt < 4; ++nt) {
      int c = nbase + nt * 16 + col;
      float b = bias[c];
      bf16x4 pk;
#pragma unroll
      for (int r = 0; r < 4; ++r) pk[r] = (short)f2b(acc[nt][r] + b);
      *(bf16x4*)(vt + c * NTOK + mbase + g * 4) = pk;
    }
  } else {
    const float QSC = 0.18033688f;  // 0.125 * log2(e): fold softmax scale + exp2 base
    unsigned short* dst = (which == 0) ? qp : kp;
#pragma unroll
    for (int nt = 0; nt < 4; ++nt) {
      int c = nbase + nt * 16 + col;
      float b = bias[c];
#pragma unroll
      for (int r = 0; r < 4; ++r) {
        int t = mbase + g * 4 + r;
        float val = acc[nt][r] + b;
        float2 csv = cs[t * 32 + ((c & 63) >> 1)];
        float pv = __shfl_xor(val, 1);
        float sn = (c & 1) ? csv.y : -csv.y;
        val = val * csv.x + pv * sn;
        if (which == 0) val *= QSC;
        dst[((c >> 6) * NTOK + t) * HD + (c & 63)] = f2b(val);
      }
    }
  }
}

// ---- flash attention: 4 heads, wave = 16 q-rows, kv-blocks of 64 ----
__global__ __launch_bounds__(256) void attn_kernel(
    const unsigned short* qp, const unsigned short* kp,
    const unsigned short* vt, unsigned short* att) {
  int head = blockIdx.y;
  int wave = threadIdx.x >> 6, lane = threadIdx.x & 63;
  int col = lane & 15, g = lane >> 4;
  int qrow = blockIdx.x * 64 + wave * 16;
  __shared__ unsigned short plds[4][16][80];  // per-wave P buffer, padded rows

  const unsigned short* qptr = qp + ((head * NTOK) + qrow + col) * HD + g * 8;
  bf16x8 qf0 = *(const bf16x8*)qptr;
  bf16x8 qf1 = *(const bf16x8*)(qptr + 32);

  f32x4 acco[4] = {};
  float mrow = -1e30f, lrow = 0.f;

  for (int kv = 0; kv < NTOK; kv += 64) {
    // S^T = K * Q^T : D-layout col = q (lane&15), rows = kv
    f32x4 st[4] = {};
#pragma unroll
    for (int mt = 0; mt < 4; ++mt) {
      const unsigned short* kptr =
          kp + ((head * NTOK) + kv + mt * 16 + col) * HD + g * 8;
      bf16x8 kf0 = *(const bf16x8*)kptr;
      bf16x8 kf1 = *(const bf16x8*)(kptr + 32);
      st[mt] = __builtin_amdgcn_mfma_f32_16x16x32_bf16(kf0, qf0, st[mt], 0, 0, 0);
      st[mt] = __builtin_amdgcn_mfma_f32_16x16x32_bf16(kf1, qf1, st[mt], 0, 0, 0);
    }
    // online softmax (log2 domain; scale folded into Q)
    float pm = mrow;
#pragma unroll
    for (int mt = 0; mt < 4; ++mt)
#pragma unroll
      for (int r = 0; r < 4; ++r) pm = fmaxf(pm, st[mt][r]);
    pm = fmaxf(pm, __shfl_xor(pm, 16));
    pm = fmaxf(pm, __shfl_xor(pm, 32));
    float fac = exp2f(mrow - pm);
    mrow = pm;
    float ps = 0.f;
    float p[4][4];
#pragma unroll
    for (int mt = 0; mt < 4; ++mt)
#pragma unroll
      for (int r = 0; r < 4; ++r) {
        p[mt][r] = exp2f(st[mt][r] - pm);
        ps += p[mt][r];
      }
    ps += __shfl_xor(ps, 16);
    ps += __shfl_xor(ps, 32);
    lrow = lrow * fac + ps;

    // P -> LDS in [q][kv] layout (each lane owns 4 consecutive kv per tile)
    asm volatile("" ::: "memory");
#pragma unroll
    for (int mt = 0; mt < 4; ++mt) {
      bf16x4 pk;
      pk[0] = (short)f2b(p[mt][0]); pk[1] = (short)f2b(p[mt][1]);
      pk[2] = (short)f2b(p[mt][2]); pk[3] = (short)f2b(p[mt][3]);
      *(bf16x4*)(&plds[wave][col][mt * 16 + g * 4]) = pk;
    }
    asm volatile("s_waitcnt lgkmcnt(0)" ::: "memory");

    // rescale O accumulators (rows of O are q = g*4+r; fac lives at lane q)
    float frow[4];
#pragma unroll
    for (int r = 0; r < 4; ++r) frow[r] = __shfl(fac, g * 4 + r);
#pragma unroll
    for (int nt = 0; nt < 4; ++nt) {
      acco[nt][0] *= frow[0]; acco[nt][1] *= frow[1];
      acco[nt][2] *= frow[2]; acco[nt][3] *= frow[3];
    }
    // O += P * V
#pragma unroll
    for (int kk = 0; kk < 2; ++kk) {
      bf16x8 pf = *(const bf16x8*)(&plds[wave][col][kk * 32 + g * 8]);
#pragma unroll
      for (int nt = 0; nt < 4; ++nt) {
        bf16x8 vf = *(const bf16x8*)(vt + (head * HD + nt * 16 + col) * NTOK +
                                     kv + kk * 32 + g * 8);
        acco[nt] = __builtin_amdgcn_mfma_f32_16x16x32_bf16(pf, vf, acco[nt], 0, 0, 0);
      }
    }
    asm volatile("" ::: "memory");
  }

  float li = 1.0f / lrow;
  float linv[4];
#pragma unroll
  for (int r = 0; r < 4; ++r) linv[r] = __shfl(li, g * 4 + r);
#pragma unroll
  for (int nt = 0; nt < 4; ++nt)
#pragma unroll
    for (int r = 0; r < 4; ++r)
      att[(qrow + g * 4 + r) * DEMB + head * HD + nt * 16 + col] =
          f2b(acco[nt][r] * linv[r]);
}

// ---- output projection: att bf16 [n][256] @ wo + bo -> f32 out ----
__global__ __launch_bounds__(256) void outproj_kernel(
    const unsigned short* att, const unsigned short* wt_o, const float* bo,
    float* out) {
  int wave = threadIdx.x >> 6, lane = threadIdx.x & 63;
  int col = lane & 15, g = lane >> 4;
  int mbase = blockIdx.x * 64 + wave * 16;
  int nbase = blockIdx.y * 64;
  f32x4 acc[4] = {};
#pragma unroll
  for (int ks = 0; ks < 256; ks += 32) {
    bf16x8 af = *(const bf16x8*)(att + (mbase + col) * 256 + ks + g * 8);
#pragma unroll
    for (int nt = 0; nt < 4; ++nt) {
      bf16x8 bf_ = *(const bf16x8*)(wt_o + (nbase + nt * 16 + col) * 256 + ks + g * 8);
      acc[nt] = __builtin_amdgcn_mfma_f32_16x16x32_bf16(af, bf_, acc[nt], 0, 0, 0);
    }
  }
#pragma unroll
  for (int nt = 0; nt < 4; ++nt) {
    int c = nbase + nt * 16 + col;
    float b = bo[c];
#pragma unroll
    for (int r = 0; r < 4; ++r)
      out[(mbase + g * 4 + r) * 256 + c] = acc[nt][r] + b;
  }
}

extern "C" void kernel_launch(void* const* d_in, const int* in_sizes, int n_in,
                              void* d_out, int out_size, void* d_ws, size_t ws_size,
                              hipStream_t stream) {
  const float* q  = (const float*)d_in[0];
  const float* k  = (const float*)d_in[1];
  const float* v  = (const float*)d_in[2];
  const float* wq = (const float*)d_in[3];
  const float* bq = (const float*)d_in[4];
  const float* wk = (const float*)d_in[5];
  const float* bk = (const float*)d_in[6];
  const float* wv = (const float*)d_in[7];
  const float* bv = (const float*)d_in[8];
  const float* wo = (const float*)d_in[9];
  const float* bo = (const float*)d_in[10];
  float* out = (float*)d_out;

  char* ws = (char*)d_ws;
  float2* cs        = (float2*)ws;                       // 4096*32*8  = 1 MB
  unsigned short* wt = (unsigned short*)(ws + (1u << 20));  // 4*64K*2 = 512 KB
  unsigned short* qp = (unsigned short*)(ws + (1u << 20) + (512u << 10));  // 2 MB
  unsigned short* kp = qp + NHEAD * NTOK * HD;           // 2 MB
  unsigned short* vt = kp + NHEAD * NTOK * HD;           // 2 MB
  unsigned short* att = vt + NHEAD * NTOK * HD;          // 2 MB

  wtrans_kernel<<<1024, 256, 0, stream>>>(wq, wk, wv, wo, wt);
  cs_kernel<<<512, 256, 0, stream>>>(cs);
  qkvproj_kernel<<<dim3(64, 4, 3), 256, 0, stream>>>(q, k, v, wt, bq, bk, bv, cs,
                                                     qp, kp, vt);
  attn_kernel<<<dim3(64, 4), 256, 0, stream>>>(qp, kp, vt, att);
  outproj_kernel<<<dim3(64, 4), 256, 0, stream>>>(att, wt + 3 * 65536, bo, out);
}

// Round 2
// 176.902 us; speedup vs baseline: 1.2209x; 1.2209x over previous
//
#include <hip/hip_runtime.h>
#include <hip/hip_bf16.h>
#include <math.h>

#define NTOK 4096
#define DEMB 256
#define NHEAD 4
#define HD 64

typedef short bf16x8 __attribute__((ext_vector_type(8)));
typedef short bf16x4 __attribute__((ext_vector_type(4)));
typedef float f32x4 __attribute__((ext_vector_type(4)));

__device__ __forceinline__ unsigned short f2b(float f) {
  union { float f; unsigned u; } v; v.f = f;
  return (unsigned short)((v.u + 0x7FFFu + ((v.u >> 16) & 1u)) >> 16);
}

// ---- prep 1: transpose+cast the 4 weight matrices to bf16 [out][in] ----
__global__ void wtrans_kernel(const float* wq, const float* wk, const float* wv,
                              const float* wo, unsigned short* wt) {
  int idx = blockIdx.x * 256 + threadIdx.x;  // 4 * 256 * 256
  int m = idx >> 16, rest = idx & 0xFFFF;
  int o = rest >> 8, i = rest & 255;
  const float* w = (m == 0) ? wq : (m == 1) ? wk : (m == 2) ? wv : wo;
  wt[idx] = f2b(w[i * 256 + o]);
}

// ---- prep 2: RoPE cos/sin table [NTOK][32] as float2(cos,sin) ----
__global__ void cs_kernel(float2* cs) {
  int idx = blockIdx.x * 256 + threadIdx.x;  // 4096*32
  int n = idx >> 5, p = idx & 31;
  int j = p & 15;
  float f = powf(10000.0f, -(float)j / 16.0f);
  float ang = ((p < 16) ? (float)(n & 63) : (float)(n >> 6)) * f;
  cs[idx] = make_float2(cosf(ang), sinf(ang));
}

// ---- fused QKV projection + bias + RoPE; z = 0:q 1:k 2:v ----
// outputs: qp/kp bf16 [h][n][d] (q pre-scaled by 0.125*log2e), vt bf16 [h][d][n]
__global__ __launch_bounds__(256) void qkvproj_kernel(
    const float* q, const float* k, const float* v, const unsigned short* wt,
    const float* bq, const float* bk, const float* bv, const float2* cs,
    unsigned short* qp, unsigned short* kp, unsigned short* vt) {
  int which = blockIdx.z;
  int wave = threadIdx.x >> 6, lane = threadIdx.x & 63;
  int col = lane & 15, g = lane >> 4;
  int mbase = blockIdx.x * 64 + wave * 16;
  int nbase = blockIdx.y * 64;
  const float* X = (which == 0) ? q : (which == 1) ? k : v;
  const unsigned short* W = wt + which * 65536;
  const float* bias = (which == 0) ? bq : (which == 1) ? bk : bv;

  f32x4 acc[4] = {};
  const float* ap0 = X + (mbase + col) * 256 + g * 8;
#pragma unroll
  for (int ks = 0; ks < 256; ks += 32) {
    float4 a0 = *(const float4*)(ap0 + ks);
    float4 a1 = *(const float4*)(ap0 + ks + 4);
    bf16x8 af;
    af[0] = (short)f2b(a0.x); af[1] = (short)f2b(a0.y);
    af[2] = (short)f2b(a0.z); af[3] = (short)f2b(a0.w);
    af[4] = (short)f2b(a1.x); af[5] = (short)f2b(a1.y);
    af[6] = (short)f2b(a1.z); af[7] = (short)f2b(a1.w);
#pragma unroll
    for (int nt = 0; nt < 4; ++nt) {
      bf16x8 bf_ = *(const bf16x8*)(W + (nbase + nt * 16 + col) * 256 + ks + g * 8);
      acc[nt] = __builtin_amdgcn_mfma_f32_16x16x32_bf16(af, bf_, acc[nt], 0, 0, 0);
    }
  }

  if (which == 2) {
    // V: bias only, store transposed vt[c][n] with 4 consecutive tokens packed
#pragma unroll
    for (int nt = 0; nt < 4; ++nt) {
      int c = nbase + nt * 16 + col;
      float b = bias[c];
      bf16x4 pk;
#pragma unroll
      for (int r = 0; r < 4; ++r) pk[r] = (short)f2b(acc[nt][r] + b);
      *(bf16x4*)(vt + c * NTOK + mbase + g * 4) = pk;
    }
  } else {
    const float QSC = 0.18033688f;  // 0.125 * log2(e): fold softmax scale + exp2 base
    unsigned short* dst = (which == 0) ? qp : kp;
#pragma unroll
    for (int nt = 0; nt < 4; ++nt) {
      int c = nbase + nt * 16 + col;
      float b = bias[c];
#pragma unroll
      for (int r = 0; r < 4; ++r) {
        int t = mbase + g * 4 + r;
        float val = acc[nt][r] + b;
        float2 csv = cs[t * 32 + ((c & 63) >> 1)];
        float pv = __shfl_xor(val, 1);
        float sn = (c & 1) ? csv.y : -csv.y;
        val = val * csv.x + pv * sn;
        if (which == 0) val *= QSC;
        dst[((c >> 6) * NTOK + t) * HD + (c & 63)] = f2b(val);
      }
    }
  }
}

// ---- flash attention with 8-way block-level KV split ----
// block = 512 threads (8 waves); each wave: same 16 q-rows, distinct 512-key
// slice; partials merged in LDS. grid = (256 q-tiles, 4 heads).
__global__ __launch_bounds__(512, 8) void attn_kernel(
    const unsigned short* qp, const unsigned short* kp,
    const unsigned short* vt, unsigned short* att) {
  int head = blockIdx.y;
  int wave = threadIdx.x >> 6, lane = threadIdx.x & 63;
  int col = lane & 15, g = lane >> 4;
  int qrow = blockIdx.x * 16;

  __shared__ float Om[8][16][64];   // per-wave unnormalized partial O
  __shared__ float Ml[8][16][2];    // per-wave (m, l) per q-row
  // P staging buffer: aliases the wave's OWN Om region (dead until after the
  // loop; same-wave DS ops are in-order so no barrier needed).
  unsigned short* pbuf = (unsigned short*)&Om[wave][0][0];  // used as [16][80]

  const unsigned short* qptr = qp + ((head * NTOK) + qrow + col) * HD + g * 8;
  bf16x8 qf0 = *(const bf16x8*)qptr;
  bf16x8 qf1 = *(const bf16x8*)(qptr + 32);

  f32x4 acco[4] = {};
  float mrow = -1e30f, lrow = 0.f;

  int kv0 = wave * 512;
  for (int kv = kv0; kv < kv0 + 512; kv += 64) {
    // S^T = K * Q^T : D-layout col = q (lane&15), rows = kv
    f32x4 st[4] = {};
#pragma unroll
    for (int mt = 0; mt < 4; ++mt) {
      const unsigned short* kptr =
          kp + ((head * NTOK) + kv + mt * 16 + col) * HD + g * 8;
      bf16x8 kf0 = *(const bf16x8*)kptr;
      bf16x8 kf1 = *(const bf16x8*)(kptr + 32);
      st[mt] = __builtin_amdgcn_mfma_f32_16x16x32_bf16(kf0, qf0, st[mt], 0, 0, 0);
      st[mt] = __builtin_amdgcn_mfma_f32_16x16x32_bf16(kf1, qf1, st[mt], 0, 0, 0);
    }
    // online softmax (log2 domain; scale folded into Q)
    float pm = mrow;
#pragma unroll
    for (int mt = 0; mt < 4; ++mt)
#pragma unroll
      for (int r = 0; r < 4; ++r) pm = fmaxf(pm, st[mt][r]);
    pm = fmaxf(pm, __shfl_xor(pm, 16));
    pm = fmaxf(pm, __shfl_xor(pm, 32));
    float fac = exp2f(mrow - pm);
    mrow = pm;
    float ps = 0.f;
    float p[4][4];
#pragma unroll
    for (int mt = 0; mt < 4; ++mt)
#pragma unroll
      for (int r = 0; r < 4; ++r) {
        p[mt][r] = exp2f(st[mt][r] - pm);
        ps += p[mt][r];
      }
    ps += __shfl_xor(ps, 16);
    ps += __shfl_xor(ps, 32);
    lrow = lrow * fac + ps;

    // P -> LDS in [q][kv] layout (each lane owns 4 consecutive kv per tile)
    asm volatile("" ::: "memory");
#pragma unroll
    for (int mt = 0; mt < 4; ++mt) {
      bf16x4 pk;
      pk[0] = (short)f2b(p[mt][0]); pk[1] = (short)f2b(p[mt][1]);
      pk[2] = (short)f2b(p[mt][2]); pk[3] = (short)f2b(p[mt][3]);
      *(bf16x4*)(&pbuf[col * 80 + mt * 16 + g * 4]) = pk;
    }
    asm volatile("s_waitcnt lgkmcnt(0)" ::: "memory");

    // rescale O accumulators (rows of O are q = g*4+r; fac lives at lane q)
    float frow[4];
#pragma unroll
    for (int r = 0; r < 4; ++r) frow[r] = __shfl(fac, g * 4 + r);
#pragma unroll
    for (int nt = 0; nt < 4; ++nt) {
      acco[nt][0] *= frow[0]; acco[nt][1] *= frow[1];
      acco[nt][2] *= frow[2]; acco[nt][3] *= frow[3];
    }
    // O += P * V
#pragma unroll
    for (int kk = 0; kk < 2; ++kk) {
      bf16x8 pf = *(const bf16x8*)(&pbuf[col * 80 + kk * 32 + g * 8]);
#pragma unroll
      for (int nt = 0; nt < 4; ++nt) {
        bf16x8 vf = *(const bf16x8*)(vt + (head * HD + nt * 16 + col) * NTOK +
                                     kv + kk * 32 + g * 8);
        acco[nt] = __builtin_amdgcn_mfma_f32_16x16x32_bf16(pf, vf, acco[nt], 0, 0, 0);
      }
    }
    asm volatile("" ::: "memory");
  }

  // write this wave's partial (overwrites its own pbuf region; same-wave
  // DS ordering guarantees the last PV reads happened first)
#pragma unroll
  for (int nt = 0; nt < 4; ++nt)
#pragma unroll
    for (int r = 0; r < 4; ++r)
      Om[wave][g * 4 + r][nt * 16 + col] = acco[nt][r];
  if (g == 0) {
    Ml[wave][col][0] = mrow;
    Ml[wave][col][1] = lrow;
  }
  __syncthreads();

  // merge 8 partials: each thread produces 2 of the 16x64 outputs
  int tid = threadIdx.x;
#pragma unroll
  for (int rep = 0; rep < 2; ++rep) {
    int o = tid + rep * 512;
    int q = o >> 6, d = o & 63;
    float mx = -1e30f;
#pragma unroll
    for (int w = 0; w < 8; ++w) mx = fmaxf(mx, Ml[w][q][0]);
    float num = 0.f, den = 0.f;
#pragma unroll
    for (int w = 0; w < 8; ++w) {
      float wgt = exp2f(Ml[w][q][0] - mx);
      num += wgt * Om[w][q][d];
      den += wgt * Ml[w][q][1];
    }
    att[(qrow + q) * DEMB + head * HD + d] = f2b(num / den);
  }
}

// ---- output projection: att bf16 [n][256] @ wo + bo -> f32 out ----
__global__ __launch_bounds__(256) void outproj_kernel(
    const unsigned short* att, const unsigned short* wt_o, const float* bo,
    float* out) {
  int wave = threadIdx.x >> 6, lane = threadIdx.x & 63;
  int col = lane & 15, g = lane >> 4;
  int mbase = blockIdx.x * 64 + wave * 16;
  int nbase = blockIdx.y * 64;
  f32x4 acc[4] = {};
#pragma unroll
  for (int ks = 0; ks < 256; ks += 32) {
    bf16x8 af = *(const bf16x8*)(att + (mbase + col) * 256 + ks + g * 8);
#pragma unroll
    for (int nt = 0; nt < 4; ++nt) {
      bf16x8 bf_ = *(const bf16x8*)(wt_o + (nbase + nt * 16 + col) * 256 + ks + g * 8);
      acc[nt] = __builtin_amdgcn_mfma_f32_16x16x32_bf16(af, bf_, acc[nt], 0, 0, 0);
    }
  }
#pragma unroll
  for (int nt = 0; nt < 4; ++nt) {
    int c = nbase + nt * 16 + col;
    float b = bo[c];
#pragma unroll
    for (int r = 0; r < 4; ++r)
      out[(mbase + g * 4 + r) * 256 + c] = acc[nt][r] + b;
  }
}

extern "C" void kernel_launch(void* const* d_in, const int* in_sizes, int n_in,
                              void* d_out, int out_size, void* d_ws, size_t ws_size,
                              hipStream_t stream) {
  const float* q  = (const float*)d_in[0];
  const float* k  = (const float*)d_in[1];
  const float* v  = (const float*)d_in[2];
  const float* wq = (const float*)d_in[3];
  const float* bq = (const float*)d_in[4];
  const float* wk = (const float*)d_in[5];
  const float* bk = (const float*)d_in[6];
  const float* wv = (const float*)d_in[7];
  const float* bv = (const float*)d_in[8];
  const float* wo = (const float*)d_in[9];
  const float* bo = (const float*)d_in[10];
  float* out = (float*)d_out;

  char* ws = (char*)d_ws;
  float2* cs        = (float2*)ws;                       // 4096*32*8  = 1 MB
  unsigned short* wt = (unsigned short*)(ws + (1u << 20));  // 4*64K*2 = 512 KB
  unsigned short* qp = (unsigned short*)(ws + (1u << 20) + (512u << 10));  // 2 MB
  unsigned short* kp = qp + NHEAD * NTOK * HD;           // 2 MB
  unsigned short* vt = kp + NHEAD * NTOK * HD;           // 2 MB
  unsigned short* att = vt + NHEAD * NTOK * HD;          // 2 MB

  wtrans_kernel<<<1024, 256, 0, stream>>>(wq, wk, wv, wo, wt);
  cs_kernel<<<512, 256, 0, stream>>>(cs);
  qkvproj_kernel<<<dim3(64, 4, 3), 256, 0, stream>>>(q, k, v, wt, bq, bk, bv, cs,
                                                     qp, kp, vt);
  attn_kernel<<<dim3(256, 4), 512, 0, stream>>>(qp, kp, vt, att);
  outproj_kernel<<<dim3(64, 4), 256, 0, stream>>>(att, wt + 3 * 65536, bo, out);
}

// Round 3
// 156.206 us; speedup vs baseline: 1.3826x; 1.1325x over previous
//
#include <hip/hip_runtime.h>
#include <hip/hip_bf16.h>
#include <math.h>

#define NTOK 4096
#define DEMB 256
#define NHEAD 4
#define HD 64

typedef short bf16x8 __attribute__((ext_vector_type(8)));
typedef short bf16x4 __attribute__((ext_vector_type(4)));
typedef float f32x4 __attribute__((ext_vector_type(4)));

__device__ __forceinline__ unsigned short f2b(float f) {
  union { float f; unsigned u; } v; v.f = f;
  return (unsigned short)((v.u + 0x7FFFu + ((v.u >> 16) & 1u)) >> 16);
}

// ---- prep 1: transpose+cast the 4 weight matrices to bf16 [out][in] ----
__global__ void wtrans_kernel(const float* wq, const float* wk, const float* wv,
                              const float* wo, unsigned short* wt) {
  int idx = blockIdx.x * 256 + threadIdx.x;  // 4 * 256 * 256
  int m = idx >> 16, rest = idx & 0xFFFF;
  int o = rest >> 8, i = rest & 255;
  const float* w = (m == 0) ? wq : (m == 1) ? wk : (m == 2) ? wv : wo;
  wt[idx] = f2b(w[i * 256 + o]);
}

// ---- prep 2: RoPE cos/sin table [NTOK][32] as float2(cos,sin) ----
__global__ void cs_kernel(float2* cs) {
  int idx = blockIdx.x * 256 + threadIdx.x;  // 4096*32
  int n = idx >> 5, p = idx & 31;
  int j = p & 15;
  float f = powf(10000.0f, -(float)j / 16.0f);
  float ang = ((p < 16) ? (float)(n & 63) : (float)(n >> 6)) * f;
  cs[idx] = make_float2(cosf(ang), sinf(ang));
}

// ---- fused QKV projection + bias + RoPE; z = 0:q 1:k 2:v ----
// outputs: qp/kp bf16 [h][n][d] (q pre-scaled by 0.125*log2e), vt bf16 [h][d][n]
__global__ __launch_bounds__(256) void qkvproj_kernel(
    const float* q, const float* k, const float* v, const unsigned short* wt,
    const float* bq, const float* bk, const float* bv, const float2* cs,
    unsigned short* qp, unsigned short* kp, unsigned short* vt) {
  int which = blockIdx.z;
  int wave = threadIdx.x >> 6, lane = threadIdx.x & 63;
  int col = lane & 15, g = lane >> 4;
  int mbase = blockIdx.x * 64 + wave * 16;
  int nbase = blockIdx.y * 64;
  const float* X = (which == 0) ? q : (which == 1) ? k : v;
  const unsigned short* W = wt + which * 65536;
  const float* bias = (which == 0) ? bq : (which == 1) ? bk : bv;

  f32x4 acc[4] = {};
  const float* ap0 = X + (mbase + col) * 256 + g * 8;
#pragma unroll
  for (int ks = 0; ks < 256; ks += 32) {
    float4 a0 = *(const float4*)(ap0 + ks);
    float4 a1 = *(const float4*)(ap0 + ks + 4);
    bf16x8 af;
    af[0] = (short)f2b(a0.x); af[1] = (short)f2b(a0.y);
    af[2] = (short)f2b(a0.z); af[3] = (short)f2b(a0.w);
    af[4] = (short)f2b(a1.x); af[5] = (short)f2b(a1.y);
    af[6] = (short)f2b(a1.z); af[7] = (short)f2b(a1.w);
#pragma unroll
    for (int nt = 0; nt < 4; ++nt) {
      bf16x8 bf_ = *(const bf16x8*)(W + (nbase + nt * 16 + col) * 256 + ks + g * 8);
      acc[nt] = __builtin_amdgcn_mfma_f32_16x16x32_bf16(af, bf_, acc[nt], 0, 0, 0);
    }
  }

  if (which == 2) {
    // V: bias only, store transposed vt[c][n] with 4 consecutive tokens packed
#pragma unroll
    for (int nt = 0; nt < 4; ++nt) {
      int c = nbase + nt * 16 + col;
      float b = bias[c];
      bf16x4 pk;
#pragma unroll
      for (int r = 0; r < 4; ++r) pk[r] = (short)f2b(acc[nt][r] + b);
      *(bf16x4*)(vt + c * NTOK + mbase + g * 4) = pk;
    }
  } else {
    const float QSC = 0.18033688f;  // 0.125 * log2(e): fold softmax scale + exp2 base
    unsigned short* dst = (which == 0) ? qp : kp;
#pragma unroll
    for (int nt = 0; nt < 4; ++nt) {
      int c = nbase + nt * 16 + col;
      float b = bias[c];
#pragma unroll
      for (int r = 0; r < 4; ++r) {
        int t = mbase + g * 4 + r;
        float val = acc[nt][r] + b;
        float2 csv = cs[t * 32 + ((c & 63) >> 1)];
        float pv = __shfl_xor(val, 1);
        float sn = (c & 1) ? csv.y : -csv.y;
        val = val * csv.x + pv * sn;
        if (which == 0) val *= QSC;
        dst[((c >> 6) * NTOK + t) * HD + (c & 63)] = f2b(val);
      }
    }
  }
}

// ---- flash attention with 8-way block-level KV split ----
// block = 512 threads (8 waves); each wave: same 16 q-rows, distinct 512-key
// slice; partials merged in LDS. grid = (256 q-tiles, 4 heads).
// min-waves/EU = 4 (128 VGPR): 8 forced VGPR<=64 and spilled ~33 MB/dispatch
// to scratch (R2 counters: WRITE_SIZE 34.8 MB, VALUBusy 20%).
__global__ __launch_bounds__(512, 4) void attn_kernel(
    const unsigned short* qp, const unsigned short* kp,
    const unsigned short* vt, unsigned short* att) {
  int head = blockIdx.y;
  int wave = threadIdx.x >> 6, lane = threadIdx.x & 63;
  int col = lane & 15, g = lane >> 4;
  int qrow = blockIdx.x * 16;

  __shared__ float Om[8][16][64];   // per-wave unnormalized partial O
  __shared__ float Ml[8][16][2];    // per-wave (m, l) per q-row
  // P staging buffer: aliases the wave's OWN Om region (dead until after the
  // loop; same-wave DS ops are in-order so no barrier needed).
  unsigned short* pbuf = (unsigned short*)&Om[wave][0][0];  // used as [16][80]

  const unsigned short* qptr = qp + ((head * NTOK) + qrow + col) * HD + g * 8;
  bf16x8 qf0 = *(const bf16x8*)qptr;
  bf16x8 qf1 = *(const bf16x8*)(qptr + 32);

  f32x4 acco[4] = {};
  float mrow = -1e30f, lrow = 0.f;

  int kv0 = wave * 512;
  for (int kv = kv0; kv < kv0 + 512; kv += 64) {
    // S^T = K * Q^T : D-layout col = q (lane&15), rows = kv
    f32x4 st[4] = {};
#pragma unroll
    for (int mt = 0; mt < 4; ++mt) {
      const unsigned short* kptr =
          kp + ((head * NTOK) + kv + mt * 16 + col) * HD + g * 8;
      bf16x8 kf0 = *(const bf16x8*)kptr;
      bf16x8 kf1 = *(const bf16x8*)(kptr + 32);
      st[mt] = __builtin_amdgcn_mfma_f32_16x16x32_bf16(kf0, qf0, st[mt], 0, 0, 0);
      st[mt] = __builtin_amdgcn_mfma_f32_16x16x32_bf16(kf1, qf1, st[mt], 0, 0, 0);
    }
    // online softmax (log2 domain; scale folded into Q)
    float pm = mrow;
#pragma unroll
    for (int mt = 0; mt < 4; ++mt)
#pragma unroll
      for (int r = 0; r < 4; ++r) pm = fmaxf(pm, st[mt][r]);
    pm = fmaxf(pm, __shfl_xor(pm, 16));
    pm = fmaxf(pm, __shfl_xor(pm, 32));
    float fac = exp2f(mrow - pm);
    mrow = pm;
    float ps = 0.f;
    float p[4][4];
#pragma unroll
    for (int mt = 0; mt < 4; ++mt)
#pragma unroll
      for (int r = 0; r < 4; ++r) {
        p[mt][r] = exp2f(st[mt][r] - pm);
        ps += p[mt][r];
      }
    ps += __shfl_xor(ps, 16);
    ps += __shfl_xor(ps, 32);
    lrow = lrow * fac + ps;

    // P -> LDS in [q][kv] layout (each lane owns 4 consecutive kv per tile)
    asm volatile("" ::: "memory");
#pragma unroll
    for (int mt = 0; mt < 4; ++mt) {
      bf16x4 pk;
      pk[0] = (short)f2b(p[mt][0]); pk[1] = (short)f2b(p[mt][1]);
      pk[2] = (short)f2b(p[mt][2]); pk[3] = (short)f2b(p[mt][3]);
      *(bf16x4*)(&pbuf[col * 80 + mt * 16 + g * 4]) = pk;
    }
    asm volatile("s_waitcnt lgkmcnt(0)" ::: "memory");

    // rescale O accumulators (rows of O are q = g*4+r; fac lives at lane q)
    float frow[4];
#pragma unroll
    for (int r = 0; r < 4; ++r) frow[r] = __shfl(fac, g * 4 + r);
#pragma unroll
    for (int nt = 0; nt < 4; ++nt) {
      acco[nt][0] *= frow[0]; acco[nt][1] *= frow[1];
      acco[nt][2] *= frow[2]; acco[nt][3] *= frow[3];
    }
    // O += P * V
#pragma unroll
    for (int kk = 0; kk < 2; ++kk) {
      bf16x8 pf = *(const bf16x8*)(&pbuf[col * 80 + kk * 32 + g * 8]);
#pragma unroll
      for (int nt = 0; nt < 4; ++nt) {
        bf16x8 vf = *(const bf16x8*)(vt + (head * HD + nt * 16 + col) * NTOK +
                                     kv + kk * 32 + g * 8);
        acco[nt] = __builtin_amdgcn_mfma_f32_16x16x32_bf16(pf, vf, acco[nt], 0, 0, 0);
      }
    }
    asm volatile("" ::: "memory");
  }

  // write this wave's partial (overwrites its own pbuf region; same-wave
  // DS ordering guarantees the last PV reads happened first)
#pragma unroll
  for (int nt = 0; nt < 4; ++nt)
#pragma unroll
    for (int r = 0; r < 4; ++r)
      Om[wave][g * 4 + r][nt * 16 + col] = acco[nt][r];
  if (g == 0) {
    Ml[wave][col][0] = mrow;
    Ml[wave][col][1] = lrow;
  }
  __syncthreads();

  // merge 8 partials: each thread produces 2 of the 16x64 outputs
  int tid = threadIdx.x;
#pragma unroll
  for (int rep = 0; rep < 2; ++rep) {
    int o = tid + rep * 512;
    int q = o >> 6, d = o & 63;
    float mx = -1e30f;
#pragma unroll
    for (int w = 0; w < 8; ++w) mx = fmaxf(mx, Ml[w][q][0]);
    float num = 0.f, den = 0.f;
#pragma unroll
    for (int w = 0; w < 8; ++w) {
      float wgt = exp2f(Ml[w][q][0] - mx);
      num += wgt * Om[w][q][d];
      den += wgt * Ml[w][q][1];
    }
    att[(qrow + q) * DEMB + head * HD + d] = f2b(num / den);
  }
}

// ---- output projection: att bf16 [n][256] @ wo + bo -> f32 out ----
__global__ __launch_bounds__(256) void outproj_kernel(
    const unsigned short* att, const unsigned short* wt_o, const float* bo,
    float* out) {
  int wave = threadIdx.x >> 6, lane = threadIdx.x & 63;
  int col = lane & 15, g = lane >> 4;
  int mbase = blockIdx.x * 64 + wave * 16;
  int nbase = blockIdx.y * 64;
  f32x4 acc[4] = {};
#pragma unroll
  for (int ks = 0; ks < 256; ks += 32) {
    bf16x8 af = *(const bf16x8*)(att + (mbase + col) * 256 + ks + g * 8);
#pragma unroll
    for (int nt = 0; nt < 4; ++nt) {
      bf16x8 bf_ = *(const bf16x8*)(wt_o + (nbase + nt * 16 + col) * 256 + ks + g * 8);
      acc[nt] = __builtin_amdgcn_mfma_f32_16x16x32_bf16(af, bf_, acc[nt], 0, 0, 0);
    }
  }
#pragma unroll
  for (int nt = 0; nt < 4; ++nt) {
    int c = nbase + nt * 16 + col;
    float b = bo[c];
#pragma unroll
    for (int r = 0; r < 4; ++r)
      out[(mbase + g * 4 + r) * 256 + c] = acc[nt][r] + b;
  }
}

extern "C" void kernel_launch(void* const* d_in, const int* in_sizes, int n_in,
                              void* d_out, int out_size, void* d_ws, size_t ws_size,
                              hipStream_t stream) {
  const float* q  = (const float*)d_in[0];
  const float* k  = (const float*)d_in[1];
  const float* v  = (const float*)d_in[2];
  const float* wq = (const float*)d_in[3];
  const float* bq = (const float*)d_in[4];
  const float* wk = (const float*)d_in[5];
  const float* bk = (const float*)d_in[6];
  const float* wv = (const float*)d_in[7];
  const float* bv = (const float*)d_in[8];
  const float* wo = (const float*)d_in[9];
  const float* bo = (const float*)d_in[10];
  float* out = (float*)d_out;

  char* ws = (char*)d_ws;
  float2* cs        = (float2*)ws;                       // 4096*32*8  = 1 MB
  unsigned short* wt = (unsigned short*)(ws + (1u << 20));  // 4*64K*2 = 512 KB
  unsigned short* qp = (unsigned short*)(ws + (1u << 20) + (512u << 10));  // 2 MB
  unsigned short* kp = qp + NHEAD * NTOK * HD;           // 2 MB
  unsigned short* vt = kp + NHEAD * NTOK * HD;           // 2 MB
  unsigned short* att = vt + NHEAD * NTOK * HD;          // 2 MB

  wtrans_kernel<<<1024, 256, 0, stream>>>(wq, wk, wv, wo, wt);
  cs_kernel<<<512, 256, 0, stream>>>(cs);
  qkvproj_kernel<<<dim3(64, 4, 3), 256, 0, stream>>>(q, k, v, wt, bq, bk, bv, cs,
                                                     qp, kp, vt);
  attn_kernel<<<dim3(256, 4), 512, 0, stream>>>(qp, kp, vt, att);
  outproj_kernel<<<dim3(64, 4), 256, 0, stream>>>(att, wt + 3 * 65536, bo, out);
}

// Round 4
// 155.812 us; speedup vs baseline: 1.3861x; 1.0025x over previous
//
#include <hip/hip_runtime.h>
#include <hip/hip_bf16.h>
#include <math.h>

#define NTOK 4096
#define DEMB 256
#define NHEAD 4
#define HD 64

typedef short bf16x8 __attribute__((ext_vector_type(8)));
typedef short bf16x4 __attribute__((ext_vector_type(4)));
typedef float f32x4 __attribute__((ext_vector_type(4)));

__device__ __forceinline__ unsigned short f2b(float f) {
  union { float f; unsigned u; } v; v.f = f;
  return (unsigned short)((v.u + 0x7FFFu + ((v.u >> 16) & 1u)) >> 16);
}
__device__ __forceinline__ unsigned pack2(float lo, float hi) {
  return (unsigned)f2b(lo) | ((unsigned)f2b(hi) << 16);
}

// ---- prep 1: transpose+cast the 4 weight matrices to bf16 [out][in] ----
__global__ void wtrans_kernel(const float* wq, const float* wk, const float* wv,
                              const float* wo, unsigned short* wt) {
  int idx = blockIdx.x * 256 + threadIdx.x;  // 4 * 256 * 256
  int m = idx >> 16, rest = idx & 0xFFFF;
  int o = rest >> 8, i = rest & 255;
  const float* w = (m == 0) ? wq : (m == 1) ? wk : (m == 2) ? wv : wo;
  wt[idx] = f2b(w[i * 256 + o]);
}

// ---- prep 2: RoPE cos/sin table [NTOK][32] as float2(cos,sin) ----
__global__ void cs_kernel(float2* cs) {
  int idx = blockIdx.x * 256 + threadIdx.x;  // 4096*32
  int n = idx >> 5, p = idx & 31;
  int j = p & 15;
  float f = powf(10000.0f, -(float)j / 16.0f);
  float ang = ((p < 16) ? (float)(n & 63) : (float)(n >> 6)) * f;
  cs[idx] = make_float2(cosf(ang), sinf(ang));
}

// ---- fused QKV projection + bias + RoPE; z = 0:q 1:k 2:v ----
// outputs: qp/kp bf16 [h][n][d] (q pre-scaled by 0.125*log2e).
// vt bf16 [h][d][n'] where the token dim is permuted within each 32-token
// block so PV's A-fragment is the attn wave's own P registers:
//   k-position kappa  <->  token 16*((kappa>>2)&1) + 4*(kappa>>3) + (kappa&3)
__global__ __launch_bounds__(256) void qkvproj_kernel(
    const float* q, const float* k, const float* v, const unsigned short* wt,
    const float* bq, const float* bk, const float* bv, const float2* cs,
    unsigned short* qp, unsigned short* kp, unsigned short* vt) {
  int which = blockIdx.z;
  int wave = threadIdx.x >> 6, lane = threadIdx.x & 63;
  int col = lane & 15, g = lane >> 4;
  int mbase = blockIdx.x * 64 + wave * 16;
  int nbase = blockIdx.y * 64;
  const float* X = (which == 0) ? q : (which == 1) ? k : v;
  const unsigned short* W = wt + which * 65536;
  const float* bias = (which == 0) ? bq : (which == 1) ? bk : bv;

  f32x4 acc[4] = {};
  const float* ap0 = X + (mbase + col) * 256 + g * 8;
#pragma unroll
  for (int ks = 0; ks < 256; ks += 32) {
    float4 a0 = *(const float4*)(ap0 + ks);
    float4 a1 = *(const float4*)(ap0 + ks + 4);
    bf16x8 af;
    af[0] = (short)f2b(a0.x); af[1] = (short)f2b(a0.y);
    af[2] = (short)f2b(a0.z); af[3] = (short)f2b(a0.w);
    af[4] = (short)f2b(a1.x); af[5] = (short)f2b(a1.y);
    af[6] = (short)f2b(a1.z); af[7] = (short)f2b(a1.w);
#pragma unroll
    for (int nt = 0; nt < 4; ++nt) {
      bf16x8 bf_ = *(const bf16x8*)(W + (nbase + nt * 16 + col) * 256 + ks + g * 8);
      acc[nt] = __builtin_amdgcn_mfma_f32_16x16x32_bf16(af, bf_, acc[nt], 0, 0, 0);
    }
  }

  if (which == 2) {
    // tokens handled by this lane: t = mbase + g*4 + r (r=0..3, consecutive)
    // permuted position: block (t>>5)*32 + 8*g + 4*((mbase>>4)&1) + r
    int kpos = ((mbase >> 5) << 5) + 8 * g + 4 * ((mbase >> 4) & 1);
#pragma unroll
    for (int nt = 0; nt < 4; ++nt) {
      int c = nbase + nt * 16 + col;
      float b = bias[c];
      bf16x4 pk;
#pragma unroll
      for (int r = 0; r < 4; ++r) pk[r] = (short)f2b(acc[nt][r] + b);
      *(bf16x4*)(vt + c * NTOK + kpos) = pk;
    }
  } else {
    const float QSC = 0.18033688f;  // 0.125 * log2(e): fold softmax scale + exp2 base
    unsigned short* dst = (which == 0) ? qp : kp;
#pragma unroll
    for (int nt = 0; nt < 4; ++nt) {
      int c = nbase + nt * 16 + col;
      float b = bias[c];
#pragma unroll
      for (int r = 0; r < 4; ++r) {
        int t = mbase + g * 4 + r;
        float val = acc[nt][r] + b;
        float2 csv = cs[t * 32 + ((c & 63) >> 1)];
        float pv = __shfl_xor(val, 1);
        float sn = (c & 1) ? csv.y : -csv.y;
        val = val * csv.x + pv * sn;
        if (which == 0) val *= QSC;
        dst[((c >> 6) * NTOK + t) * HD + (c & 63)] = f2b(val);
      }
    }
  }
}

// ---- flash attention with 8-way block-level KV split ----
// block = 512 threads (8 waves); each wave: same 16 q-rows, distinct 512-key
// slice; partials merged in LDS. grid = (256 q-tiles, 4 heads).
// P stays in registers: V's permuted token layout makes the PV A-fragment
// the lane's own packed p values (no LDS roundtrip, no cross-lane movement).
__global__ __launch_bounds__(512, 4) void attn_kernel(
    const unsigned short* qp, const unsigned short* kp,
    const unsigned short* vt, unsigned short* att) {
  int head = blockIdx.y;
  int wave = threadIdx.x >> 6, lane = threadIdx.x & 63;
  int col = lane & 15, g = lane >> 4;
  int qrow = blockIdx.x * 16;

  __shared__ float Om[8][16][64];   // per-wave unnormalized partial O
  __shared__ float Ml[8][16][2];    // per-wave (m, l) per q-row

  const unsigned short* qptr = qp + ((head * NTOK) + qrow + col) * HD + g * 8;
  bf16x8 qf0 = *(const bf16x8*)qptr;
  bf16x8 qf1 = *(const bf16x8*)(qptr + 32);

  f32x4 acco[4] = {};
  float mrow = -1e30f, lrow = 0.f;

  int kv0 = wave * 512;
  for (int kv = kv0; kv < kv0 + 512; kv += 64) {
    // S^T = K * Q^T : D-layout col = q (lane&15), rows = kv
    f32x4 st[4] = {};
#pragma unroll
    for (int mt = 0; mt < 4; ++mt) {
      const unsigned short* kptr =
          kp + ((head * NTOK) + kv + mt * 16 + col) * HD + g * 8;
      bf16x8 kf0 = *(const bf16x8*)kptr;
      bf16x8 kf1 = *(const bf16x8*)(kptr + 32);
      st[mt] = __builtin_amdgcn_mfma_f32_16x16x32_bf16(kf0, qf0, st[mt], 0, 0, 0);
      st[mt] = __builtin_amdgcn_mfma_f32_16x16x32_bf16(kf1, qf1, st[mt], 0, 0, 0);
    }
    // online softmax (log2 domain; scale folded into Q)
    float pm = mrow;
#pragma unroll
    for (int mt = 0; mt < 4; ++mt)
#pragma unroll
      for (int r = 0; r < 4; ++r) pm = fmaxf(pm, st[mt][r]);
    pm = fmaxf(pm, __shfl_xor(pm, 16));
    pm = fmaxf(pm, __shfl_xor(pm, 32));
    float fac = exp2f(mrow - pm);
    mrow = pm;
    float ps = 0.f;
    float p[4][4];
#pragma unroll
    for (int mt = 0; mt < 4; ++mt)
#pragma unroll
      for (int r = 0; r < 4; ++r) {
        p[mt][r] = exp2f(st[mt][r] - pm);
        ps += p[mt][r];
      }
    ps += __shfl_xor(ps, 16);
    ps += __shfl_xor(ps, 32);
    lrow = lrow * fac + ps;

    // rescale O accumulators (rows of O are q = g*4+r; fac lives at lane q)
    float frow[4];
#pragma unroll
    for (int r = 0; r < 4; ++r) frow[r] = __shfl(fac, g * 4 + r);
#pragma unroll
    for (int nt = 0; nt < 4; ++nt) {
      acco[nt][0] *= frow[0]; acco[nt][1] *= frow[1];
      acco[nt][2] *= frow[2]; acco[nt][3] *= frow[3];
    }
    // O += P * V : A-fragment = own p registers packed (V token-permuted)
#pragma unroll
    for (int kk = 0; kk < 2; ++kk) {
      union { unsigned u[4]; bf16x8 v; } pf;
      pf.u[0] = pack2(p[2 * kk][0], p[2 * kk][1]);
      pf.u[1] = pack2(p[2 * kk][2], p[2 * kk][3]);
      pf.u[2] = pack2(p[2 * kk + 1][0], p[2 * kk + 1][1]);
      pf.u[3] = pack2(p[2 * kk + 1][2], p[2 * kk + 1][3]);
#pragma unroll
      for (int nt = 0; nt < 4; ++nt) {
        bf16x8 vf = *(const bf16x8*)(vt + (head * HD + nt * 16 + col) * NTOK +
                                     kv + kk * 32 + g * 8);
        acco[nt] = __builtin_amdgcn_mfma_f32_16x16x32_bf16(pf.v, vf, acco[nt], 0, 0, 0);
      }
    }
  }

  // write this wave's partial
#pragma unroll
  for (int nt = 0; nt < 4; ++nt)
#pragma unroll
    for (int r = 0; r < 4; ++r)
      Om[wave][g * 4 + r][nt * 16 + col] = acco[nt][r];
  if (g == 0) {
    Ml[wave][col][0] = mrow;
    Ml[wave][col][1] = lrow;
  }
  __syncthreads();

  // merge 8 partials: each thread produces 2 of the 16x64 outputs
  int tid = threadIdx.x;
#pragma unroll
  for (int rep = 0; rep < 2; ++rep) {
    int o = tid + rep * 512;
    int q = o >> 6, d = o & 63;
    float mx = -1e30f;
#pragma unroll
    for (int w = 0; w < 8; ++w) mx = fmaxf(mx, Ml[w][q][0]);
    float num = 0.f, den = 0.f;
#pragma unroll
    for (int w = 0; w < 8; ++w) {
      float wgt = exp2f(Ml[w][q][0] - mx);
      num += wgt * Om[w][q][d];
      den += wgt * Ml[w][q][1];
    }
    att[(qrow + q) * DEMB + head * HD + d] = f2b(num / den);
  }
}

// ---- output projection: att bf16 [n][256] @ wo + bo -> f32 out ----
__global__ __launch_bounds__(256) void outproj_kernel(
    const unsigned short* att, const unsigned short* wt_o, const float* bo,
    float* out) {
  int wave = threadIdx.x >> 6, lane = threadIdx.x & 63;
  int col = lane & 15, g = lane >> 4;
  int mbase = blockIdx.x * 64 + wave * 16;
  int nbase = blockIdx.y * 64;
  f32x4 acc[4] = {};
#pragma unroll
  for (int ks = 0; ks < 256; ks += 32) {
    bf16x8 af = *(const bf16x8*)(att + (mbase + col) * 256 + ks + g * 8);
#pragma unroll
    for (int nt = 0; nt < 4; ++nt) {
      bf16x8 bf_ = *(const bf16x8*)(wt_o + (nbase + nt * 16 + col) * 256 + ks + g * 8);
      acc[nt] = __builtin_amdgcn_mfma_f32_16x16x32_bf16(af, bf_, acc[nt], 0, 0, 0);
    }
  }
#pragma unroll
  for (int nt = 0; nt < 4; ++nt) {
    int c = nbase + nt * 16 + col;
    float b = bo[c];
#pragma unroll
    for (int r = 0; r < 4; ++r)
      out[(mbase + g * 4 + r) * 256 + c] = acc[nt][r] + b;
  }
}

extern "C" void kernel_launch(void* const* d_in, const int* in_sizes, int n_in,
                              void* d_out, int out_size, void* d_ws, size_t ws_size,
                              hipStream_t stream) {
  const float* q  = (const float*)d_in[0];
  const float* k  = (const float*)d_in[1];
  const float* v  = (const float*)d_in[2];
  const float* wq = (const float*)d_in[3];
  const float* bq = (const float*)d_in[4];
  const float* wk = (const float*)d_in[5];
  const float* bk = (const float*)d_in[6];
  const float* wv = (const float*)d_in[7];
  const float* bv = (const float*)d_in[8];
  const float* wo = (const float*)d_in[9];
  const float* bo = (const float*)d_in[10];
  float* out = (float*)d_out;

  char* ws = (char*)d_ws;
  float2* cs        = (float2*)ws;                       // 4096*32*8  = 1 MB
  unsigned short* wt = (unsigned short*)(ws + (1u << 20));  // 4*64K*2 = 512 KB
  unsigned short* qp = (unsigned short*)(ws + (1u << 20) + (512u << 10));  // 2 MB
  unsigned short* kp = qp + NHEAD * NTOK * HD;           // 2 MB
  unsigned short* vt = kp + NHEAD * NTOK * HD;           // 2 MB
  unsigned short* att = vt + NHEAD * NTOK * HD;          // 2 MB

  wtrans_kernel<<<1024, 256, 0, stream>>>(wq, wk, wv, wo, wt);
  cs_kernel<<<512, 256, 0, stream>>>(cs);
  qkvproj_kernel<<<dim3(64, 4, 3), 256, 0, stream>>>(q, k, v, wt, bq, bk, bv, cs,
                                                     qp, kp, vt);
  attn_kernel<<<dim3(256, 4), 512, 0, stream>>>(qp, kp, vt, att);
  outproj_kernel<<<dim3(64, 4), 256, 0, stream>>>(att, wt + 3 * 65536, bo, out);
}

// Round 5
// 155.721 us; speedup vs baseline: 1.3869x; 1.0006x over previous
//
#include <hip/hip_runtime.h>
#include <hip/hip_bf16.h>
#include <math.h>

#define NTOK 4096
#define DEMB 256
#define NHEAD 4
#define HD 64

typedef short bf16x8 __attribute__((ext_vector_type(8)));
typedef short bf16x4 __attribute__((ext_vector_type(4)));
typedef float f32x4 __attribute__((ext_vector_type(4)));

__device__ __forceinline__ unsigned short f2b(float f) {
  union { float f; unsigned u; } v; v.f = f;
  return (unsigned short)((v.u + 0x7FFFu + ((v.u >> 16) & 1u)) >> 16);
}
__device__ __forceinline__ unsigned pack2(float lo, float hi) {
  return (unsigned)f2b(lo) | ((unsigned)f2b(hi) << 16);
}

// ---- prep 1: transpose+cast the 4 weight matrices to bf16 [out][in] ----
__global__ void wtrans_kernel(const float* wq, const float* wk, const float* wv,
                              const float* wo, unsigned short* wt) {
  int idx = blockIdx.x * 256 + threadIdx.x;  // 4 * 256 * 256
  int m = idx >> 16, rest = idx & 0xFFFF;
  int o = rest >> 8, i = rest & 255;
  const float* w = (m == 0) ? wq : (m == 1) ? wk : (m == 2) ? wv : wo;
  wt[idx] = f2b(w[i * 256 + o]);
}

// ---- prep 2: RoPE cos/sin table [NTOK][32] as float2(cos,sin) ----
__global__ void cs_kernel(float2* cs) {
  int idx = blockIdx.x * 256 + threadIdx.x;  // 4096*32
  int n = idx >> 5, p = idx & 31;
  int j = p & 15;
  float f = powf(10000.0f, -(float)j / 16.0f);
  float ang = ((p < 16) ? (float)(n & 63) : (float)(n >> 6)) * f;
  cs[idx] = make_float2(cosf(ang), sinf(ang));
}

// ---- fused QKV projection + bias + RoPE; z = 0:q 1:k 2:v ----
// outputs: qp/kp bf16 [h][n][d] (q pre-scaled by 0.125*log2e).
// vt bf16 [h][d][n'] where the token dim is permuted within each 32-token
// block so PV's A-fragment is the attn wave's own P registers:
//   k-position kappa  <->  token 16*((kappa>>2)&1) + 4*(kappa>>3) + (kappa&3)
__global__ __launch_bounds__(256) void qkvproj_kernel(
    const float* q, const float* k, const float* v, const unsigned short* wt,
    const float* bq, const float* bk, const float* bv, const float2* cs,
    unsigned short* qp, unsigned short* kp, unsigned short* vt) {
  int which = blockIdx.z;
  int wave = threadIdx.x >> 6, lane = threadIdx.x & 63;
  int col = lane & 15, g = lane >> 4;
  int mbase = blockIdx.x * 64 + wave * 16;
  int nbase = blockIdx.y * 64;
  const float* X = (which == 0) ? q : (which == 1) ? k : v;
  const unsigned short* W = wt + which * 65536;
  const float* bias = (which == 0) ? bq : (which == 1) ? bk : bv;

  f32x4 acc[4] = {};
  const float* ap0 = X + (mbase + col) * 256 + g * 8;
#pragma unroll
  for (int ks = 0; ks < 256; ks += 32) {
    float4 a0 = *(const float4*)(ap0 + ks);
    float4 a1 = *(const float4*)(ap0 + ks + 4);
    bf16x8 af;
    af[0] = (short)f2b(a0.x); af[1] = (short)f2b(a0.y);
    af[2] = (short)f2b(a0.z); af[3] = (short)f2b(a0.w);
    af[4] = (short)f2b(a1.x); af[5] = (short)f2b(a1.y);
    af[6] = (short)f2b(a1.z); af[7] = (short)f2b(a1.w);
#pragma unroll
    for (int nt = 0; nt < 4; ++nt) {
      bf16x8 bf_ = *(const bf16x8*)(W + (nbase + nt * 16 + col) * 256 + ks + g * 8);
      acc[nt] = __builtin_amdgcn_mfma_f32_16x16x32_bf16(af, bf_, acc[nt], 0, 0, 0);
    }
  }

  if (which == 2) {
    // tokens handled by this lane: t = mbase + g*4 + r (r=0..3, consecutive)
    // permuted position: block (t>>5)*32 + 8*g + 4*((mbase>>4)&1) + r
    int kpos = ((mbase >> 5) << 5) + 8 * g + 4 * ((mbase >> 4) & 1);
#pragma unroll
    for (int nt = 0; nt < 4; ++nt) {
      int c = nbase + nt * 16 + col;
      float b = bias[c];
      bf16x4 pk;
#pragma unroll
      for (int r = 0; r < 4; ++r) pk[r] = (short)f2b(acc[nt][r] + b);
      *(bf16x4*)(vt + c * NTOK + kpos) = pk;
    }
  } else {
    const float QSC = 0.18033688f;  // 0.125 * log2(e): fold softmax scale + exp2 base
    unsigned short* dst = (which == 0) ? qp : kp;
#pragma unroll
    for (int nt = 0; nt < 4; ++nt) {
      int c = nbase + nt * 16 + col;
      float b = bias[c];
#pragma unroll
      for (int r = 0; r < 4; ++r) {
        int t = mbase + g * 4 + r;
        float val = acc[nt][r] + b;
        float2 csv = cs[t * 32 + ((c & 63) >> 1)];
        float pv = __shfl_xor(val, 1);
        float sn = (c & 1) ? csv.y : -csv.y;
        val = val * csv.x + pv * sn;
        if (which == 0) val *= QSC;
        dst[((c >> 6) * NTOK + t) * HD + (c & 63)] = f2b(val);
      }
    }
  }
}

// ---- flash attention with 8-way block-level KV split ----
// block = 512 threads (8 waves); each wave: same 16 q-rows, distinct 512-key
// slice; partials merged in LDS.
// XCD-locality remap: linear block id -> XCD is id%8 (measured m09). Map
// head = xcd>>1 so each XCD serves ONE head; its K/V slice (1 MB) + Q/att
// (~0.6 MB) stay L2-resident instead of thrashing 4 heads * 2 MB against
// the 4 MB per-XCD L2 (R4: loop-structure changes had zero effect -> the
// limiter was L2-miss traffic served by Infinity Cache).
__global__ __launch_bounds__(512, 4) void attn_kernel(
    const unsigned short* qp, const unsigned short* kp,
    const unsigned short* vt, unsigned short* att) {
  int id = blockIdx.x + (blockIdx.y << 8);  // gridDim = (256, 4)
  int xcd = id & 7;
  int head = xcd >> 1;                       // 2 XCDs per head
  int qrow = ((((id >> 3) << 1) | (xcd & 1))) * 16;
  int wave = threadIdx.x >> 6, lane = threadIdx.x & 63;
  int col = lane & 15, g = lane >> 4;

  __shared__ float Om[8][16][64];   // per-wave unnormalized partial O
  __shared__ float Ml[8][16][2];    // per-wave (m, l) per q-row

  const unsigned short* qptr = qp + ((head * NTOK) + qrow + col) * HD + g * 8;
  bf16x8 qf0 = *(const bf16x8*)qptr;
  bf16x8 qf1 = *(const bf16x8*)(qptr + 32);

  f32x4 acco[4] = {};
  float mrow = -1e30f, lrow = 0.f;

  int kv0 = wave * 512;
  for (int kv = kv0; kv < kv0 + 512; kv += 64) {
    // S^T = K * Q^T : D-layout col = q (lane&15), rows = kv
    f32x4 st[4] = {};
#pragma unroll
    for (int mt = 0; mt < 4; ++mt) {
      const unsigned short* kptr =
          kp + ((head * NTOK) + kv + mt * 16 + col) * HD + g * 8;
      bf16x8 kf0 = *(const bf16x8*)kptr;
      bf16x8 kf1 = *(const bf16x8*)(kptr + 32);
      st[mt] = __builtin_amdgcn_mfma_f32_16x16x32_bf16(kf0, qf0, st[mt], 0, 0, 0);
      st[mt] = __builtin_amdgcn_mfma_f32_16x16x32_bf16(kf1, qf1, st[mt], 0, 0, 0);
    }
    // online softmax (log2 domain; scale folded into Q)
    float pm = mrow;
#pragma unroll
    for (int mt = 0; mt < 4; ++mt)
#pragma unroll
      for (int r = 0; r < 4; ++r) pm = fmaxf(pm, st[mt][r]);
    pm = fmaxf(pm, __shfl_xor(pm, 16));
    pm = fmaxf(pm, __shfl_xor(pm, 32));
    float fac = exp2f(mrow - pm);
    mrow = pm;
    float ps = 0.f;
    float p[4][4];
#pragma unroll
    for (int mt = 0; mt < 4; ++mt)
#pragma unroll
      for (int r = 0; r < 4; ++r) {
        p[mt][r] = exp2f(st[mt][r] - pm);
        ps += p[mt][r];
      }
    ps += __shfl_xor(ps, 16);
    ps += __shfl_xor(ps, 32);
    lrow = lrow * fac + ps;

    // rescale O accumulators (rows of O are q = g*4+r; fac lives at lane q)
    float frow[4];
#pragma unroll
    for (int r = 0; r < 4; ++r) frow[r] = __shfl(fac, g * 4 + r);
#pragma unroll
    for (int nt = 0; nt < 4; ++nt) {
      acco[nt][0] *= frow[0]; acco[nt][1] *= frow[1];
      acco[nt][2] *= frow[2]; acco[nt][3] *= frow[3];
    }
    // O += P * V : A-fragment = own p registers packed (V token-permuted)
#pragma unroll
    for (int kk = 0; kk < 2; ++kk) {
      union { unsigned u[4]; bf16x8 v; } pf;
      pf.u[0] = pack2(p[2 * kk][0], p[2 * kk][1]);
      pf.u[1] = pack2(p[2 * kk][2], p[2 * kk][3]);
      pf.u[2] = pack2(p[2 * kk + 1][0], p[2 * kk + 1][1]);
      pf.u[3] = pack2(p[2 * kk + 1][2], p[2 * kk + 1][3]);
#pragma unroll
      for (int nt = 0; nt < 4; ++nt) {
        bf16x8 vf = *(const bf16x8*)(vt + (head * HD + nt * 16 + col) * NTOK +
                                     kv + kk * 32 + g * 8);
        acco[nt] = __builtin_amdgcn_mfma_f32_16x16x32_bf16(pf.v, vf, acco[nt], 0, 0, 0);
      }
    }
  }

  // write this wave's partial
#pragma unroll
  for (int nt = 0; nt < 4; ++nt)
#pragma unroll
    for (int r = 0; r < 4; ++r)
      Om[wave][g * 4 + r][nt * 16 + col] = acco[nt][r];
  if (g == 0) {
    Ml[wave][col][0] = mrow;
    Ml[wave][col][1] = lrow;
  }
  __syncthreads();

  // merge 8 partials: each thread produces 2 of the 16x64 outputs
  int tid = threadIdx.x;
#pragma unroll
  for (int rep = 0; rep < 2; ++rep) {
    int o = tid + rep * 512;
    int q = o >> 6, d = o & 63;
    float mx = -1e30f;
#pragma unroll
    for (int w = 0; w < 8; ++w) mx = fmaxf(mx, Ml[w][q][0]);
    float num = 0.f, den = 0.f;
#pragma unroll
    for (int w = 0; w < 8; ++w) {
      float wgt = exp2f(Ml[w][q][0] - mx);
      num += wgt * Om[w][q][d];
      den += wgt * Ml[w][q][1];
    }
    att[(qrow + q) * DEMB + head * HD + d] = f2b(num / den);
  }
}

// ---- output projection: att bf16 [n][256] @ wo + bo -> f32 out ----
__global__ __launch_bounds__(256) void outproj_kernel(
    const unsigned short* att, const unsigned short* wt_o, const float* bo,
    float* out) {
  int wave = threadIdx.x >> 6, lane = threadIdx.x & 63;
  int col = lane & 15, g = lane >> 4;
  int mbase = blockIdx.x * 64 + wave * 16;
  int nbase = blockIdx.y * 64;
  f32x4 acc[4] = {};
#pragma unroll
  for (int ks = 0; ks < 256; ks += 32) {
    bf16x8 af = *(const bf16x8*)(att + (mbase + col) * 256 + ks + g * 8);
#pragma unroll
    for (int nt = 0; nt < 4; ++nt) {
      bf16x8 bf_ = *(const bf16x8*)(wt_o + (nbase + nt * 16 + col) * 256 + ks + g * 8);
      acc[nt] = __builtin_amdgcn_mfma_f32_16x16x32_bf16(af, bf_, acc[nt], 0, 0, 0);
    }
  }
#pragma unroll
  for (int nt = 0; nt < 4; ++nt) {
    int c = nbase + nt * 16 + col;
    float b = bo[c];
#pragma unroll
    for (int r = 0; r < 4; ++r)
      out[(mbase + g * 4 + r) * 256 + c] = acc[nt][r] + b;
  }
}

extern "C" void kernel_launch(void* const* d_in, const int* in_sizes, int n_in,
                              void* d_out, int out_size, void* d_ws, size_t ws_size,
                              hipStream_t stream) {
  const float* q  = (const float*)d_in[0];
  const float* k  = (const float*)d_in[1];
  const float* v  = (const float*)d_in[2];
  const float* wq = (const float*)d_in[3];
  const float* bq = (const float*)d_in[4];
  const float* wk = (const float*)d_in[5];
  const float* bk = (const float*)d_in[6];
  const float* wv = (const float*)d_in[7];
  const float* bv = (const float*)d_in[8];
  const float* wo = (const float*)d_in[9];
  const float* bo = (const float*)d_in[10];
  float* out = (float*)d_out;

  char* ws = (char*)d_ws;
  float2* cs        = (float2*)ws;                       // 4096*32*8  = 1 MB
  unsigned short* wt = (unsigned short*)(ws + (1u << 20));  // 4*64K*2 = 512 KB
  unsigned short* qp = (unsigned short*)(ws + (1u << 20) + (512u << 10));  // 2 MB
  unsigned short* kp = qp + NHEAD * NTOK * HD;           // 2 MB
  unsigned short* vt = kp + NHEAD * NTOK * HD;           // 2 MB
  unsigned short* att = vt + NHEAD * NTOK * HD;          // 2 MB

  wtrans_kernel<<<1024, 256, 0, stream>>>(wq, wk, wv, wo, wt);
  cs_kernel<<<512, 256, 0, stream>>>(cs);
  qkvproj_kernel<<<dim3(64, 4, 3), 256, 0, stream>>>(q, k, v, wt, bq, bk, bv, cs,
                                                     qp, kp, vt);
  attn_kernel<<<dim3(256, 4), 512, 0, stream>>>(qp, kp, vt, att);
  outproj_kernel<<<dim3(64, 4), 256, 0, stream>>>(att, wt + 3 * 65536, bo, out);
}

// Round 7
// 82.690 us; speedup vs baseline: 2.6118x; 1.8832x over previous
//
#include <hip/hip_runtime.h>
#include <hip/hip_bf16.h>
#include <math.h>

#define NTOK 4096
#define DEMB 256
#define NHEAD 4
#define HD 64

typedef short bf16x8 __attribute__((ext_vector_type(8)));
typedef short bf16x4 __attribute__((ext_vector_type(4)));
typedef float f32x4 __attribute__((ext_vector_type(4)));

__device__ __forceinline__ unsigned short f2b(float f) {
  union { float f; unsigned u; } v; v.f = f;
  return (unsigned short)((v.u + 0x7FFFu + ((v.u >> 16) & 1u)) >> 16);
}
__device__ __forceinline__ unsigned pack2(float lo, float hi) {
  return (unsigned)f2b(lo) | ((unsigned)f2b(hi) << 16);
}

// ---- prep 1: transpose+cast the 4 weight matrices to bf16 [out][in] ----
__global__ void wtrans_kernel(const float* wq, const float* wk, const float* wv,
                              const float* wo, unsigned short* wt) {
  int idx = blockIdx.x * 256 + threadIdx.x;  // 4 * 256 * 256
  int m = idx >> 16, rest = idx & 0xFFFF;
  int o = rest >> 8, i = rest & 255;
  const float* w = (m == 0) ? wq : (m == 1) ? wk : (m == 2) ? wv : wo;
  wt[idx] = f2b(w[i * 256 + o]);
}

// ---- prep 2: RoPE cos/sin table [NTOK][32] as float2(cos,sin) ----
__global__ void cs_kernel(float2* cs) {
  int idx = blockIdx.x * 256 + threadIdx.x;  // 4096*32
  int n = idx >> 5, p = idx & 31;
  int j = p & 15;
  float f = powf(10000.0f, -(float)j / 16.0f);
  float ang = ((p < 16) ? (float)(n & 63) : (float)(n >> 6)) * f;
  cs[idx] = make_float2(cosf(ang), sinf(ang));
}

// ---- fused QKV projection + bias + RoPE; z = 0:q 1:k 2:v ----
// outputs: qp/kp bf16 [h][n][d] (q pre-scaled by 0.125*log2e).
// vt bf16 [h][d][n'] where the token dim is permuted within each 32-token
// block so PV's A-fragment is the attn wave's own P registers:
//   k-position kappa  <->  token 16*((kappa>>2)&1) + 4*(kappa>>3) + (kappa&3)
__global__ __launch_bounds__(256) void qkvproj_kernel(
    const float* q, const float* k, const float* v, const unsigned short* wt,
    const float* bq, const float* bk, const float* bv, const float2* cs,
    unsigned short* qp, unsigned short* kp, unsigned short* vt) {
  int which = blockIdx.z;
  int wave = threadIdx.x >> 6, lane = threadIdx.x & 63;
  int col = lane & 15, g = lane >> 4;
  int mbase = blockIdx.x * 64 + wave * 16;
  int nbase = blockIdx.y * 64;
  const float* X = (which == 0) ? q : (which == 1) ? k : v;
  const unsigned short* W = wt + which * 65536;
  const float* bias = (which == 0) ? bq : (which == 1) ? bk : bv;

  f32x4 acc[4] = {};
  const float* ap0 = X + (mbase + col) * 256 + g * 8;
#pragma unroll
  for (int ks = 0; ks < 256; ks += 32) {
    float4 a0 = *(const float4*)(ap0 + ks);
    float4 a1 = *(const float4*)(ap0 + ks + 4);
    bf16x8 af;
    af[0] = (short)f2b(a0.x); af[1] = (short)f2b(a0.y);
    af[2] = (short)f2b(a0.z); af[3] = (short)f2b(a0.w);
    af[4] = (short)f2b(a1.x); af[5] = (short)f2b(a1.y);
    af[6] = (short)f2b(a1.z); af[7] = (short)f2b(a1.w);
#pragma unroll
    for (int nt = 0; nt < 4; ++nt) {
      bf16x8 bf_ = *(const bf16x8*)(W + (nbase + nt * 16 + col) * 256 + ks + g * 8);
      acc[nt] = __builtin_amdgcn_mfma_f32_16x16x32_bf16(af, bf_, acc[nt], 0, 0, 0);
    }
  }

  if (which == 2) {
    // tokens handled by this lane: t = mbase + g*4 + r (r=0..3, consecutive)
    // permuted position: block (t>>5)*32 + 8*g + 4*((mbase>>4)&1) + r
    int kpos = ((mbase >> 5) << 5) + 8 * g + 4 * ((mbase >> 4) & 1);
#pragma unroll
    for (int nt = 0; nt < 4; ++nt) {
      int c = nbase + nt * 16 + col;
      float b = bias[c];
      bf16x4 pk;
#pragma unroll
      for (int r = 0; r < 4; ++r) pk[r] = (short)f2b(acc[nt][r] + b);
      *(bf16x4*)(vt + c * NTOK + kpos) = pk;
    }
  } else {
    const float QSC = 0.18033688f;  // 0.125 * log2(e): fold softmax scale + exp2 base
    unsigned short* dst = (which == 0) ? qp : kp;
#pragma unroll
    for (int nt = 0; nt < 4; ++nt) {
      int c = nbase + nt * 16 + col;
      float b = bias[c];
#pragma unroll
      for (int r = 0; r < 4; ++r) {
        int t = mbase + g * 4 + r;
        float val = acc[nt][r] + b;
        float2 csv = cs[t * 32 + ((c & 63) >> 1)];
        float pv = __shfl_xor(val, 1);
        float sn = (c & 1) ? csv.y : -csv.y;
        val = val * csv.x + pv * sn;
        if (which == 0) val *= QSC;
        dst[((c >> 6) * NTOK + t) * HD + (c & 63)] = f2b(val);
      }
    }
  }
}

// ---- flash attention, LDS-staged two-level structure ----
// block = 512 thr = 8 waves = 2 q-groups x 4 kv-groups; block = 64 q-rows.
// wave (qg,kg): 32 q-rows, kv slice [kg*1024, +1024), tiles of 64 keys
// double-buffered in LDS (XOR-swizzled rows), staged global->reg->LDS one
// tile ahead. kv-partials merged in LDS. grid = 256 blocks, XCD->head map.
// P-pack: f2b/pack2 (RNE). R6 used v_cvt_pk_bf16_f32 here and failed
// absmax 2.4e-4 (8x R5's 3e-5): truncating pack -> one-sided P error that
// accumulates linearly over the 4096-key sum vs RNE's sqrt(N) cancellation.
__global__ __launch_bounds__(512, 2) void attn_kernel(
    const unsigned short* qp, const unsigned short* kp,
    const unsigned short* vt, unsigned short* att) {
  __shared__ alignas(16) unsigned char lds[131072];  // K: [kg][buf][8KB], V: +64KB
  int id = blockIdx.x;
  int xcd = id & 7;
  int head = xcd >> 1;                     // 2 XCDs per head (L2 locality)
  int qtile = ((id >> 3) << 1) | (xcd & 1);  // 0..63
  int qb = qtile * 64;
  int w = threadIdx.x >> 6, lane = threadIdx.x & 63;
  int kg = w & 3, qg = w >> 2;
  int col = lane & 15, g = lane >> 4;

  const unsigned kb0 = (unsigned)(kg * 2) * 8192u;
  const unsigned vb0 = 65536u + (unsigned)(kg * 2) * 8192u;
  const unsigned short* kgp = kp + (head * NTOK + kg * 1024) * HD;
  const unsigned short* vgp = vt + head * HD * NTOK + kg * 1024;

  int tid2 = qg * 64 + lane;  // 0..127 within the kg-pair (staging id)
  bf16x8 skr[4], svr[4];

  auto stage_issue = [&](int t) {
    const unsigned short* kq = kgp + t * 64 * HD;
    const unsigned short* vq = vgp + t * 64;
#pragma unroll
    for (int i = 0; i < 4; ++i) {
      int c = tid2 + i * 128, tok = c >> 3, part = c & 7;
      skr[i] = *(const bf16x8*)(kq + tok * HD + part * 8);
      svr[i] = *(const bf16x8*)(vq + tok * NTOK + part * 8);  // tok = d-row here
    }
  };
  auto stage_write = [&](int buf) {
    unsigned kb = kb0 + (unsigned)buf * 8192u, vb = vb0 + (unsigned)buf * 8192u;
#pragma unroll
    for (int i = 0; i < 4; ++i) {
      int c = tid2 + i * 128, tok = c >> 3, part = c & 7;
      unsigned off = (unsigned)(tok * 128) + (unsigned)((part * 16) ^ ((tok & 7) << 4));
      *(bf16x8*)(lds + kb + off) = skr[i];
      *(bf16x8*)(lds + vb + off) = svr[i];
    }
  };

  // Q fragments: 32 q-rows -> qf[qt][half]
  bf16x8 qf[2][2];
  {
    const unsigned short* qr = qp + (head * NTOK + qb + qg * 32) * HD;
#pragma unroll
    for (int qt = 0; qt < 2; ++qt)
#pragma unroll
      for (int h2 = 0; h2 < 2; ++h2)
        qf[qt][h2] = *(const bf16x8*)(qr + (qt * 16 + col) * HD + h2 * 32 + g * 8);
  }

  stage_issue(0);
  stage_write(0);       // compiler inserts vmcnt wait
  stage_issue(1);
  __syncthreads();

  f32x4 acco[4][2] = {};
  float mrow[2] = {-1e30f, -1e30f}, lrow[2] = {0.f, 0.f};

  for (int t = 0; t < 16; ++t) {
    int cur = t & 1;
    if (t < 15) {
      stage_write(cur ^ 1);            // buf read last iter; barrier passed
      if (t < 14) stage_issue(t + 2);  // overlap loads with compute below
    }
    unsigned kb = kb0 + (unsigned)cur * 8192u, vb = vb0 + (unsigned)cur * 8192u;

    // S^T = K * Q^T : D col=q, rows=kv
    f32x4 st[4][2] = {};
#pragma unroll
    for (int mt = 0; mt < 4; ++mt) {
      int tok = mt * 16 + col;
      unsigned ro = kb + (unsigned)(tok * 128) + (unsigned)((g * 16) ^ ((tok & 7) << 4));
      bf16x8 kf0 = *(const bf16x8*)(lds + ro);
      bf16x8 kf1 = *(const bf16x8*)(lds + (ro ^ 64u));
#pragma unroll
      for (int qt = 0; qt < 2; ++qt) {
        st[mt][qt] = __builtin_amdgcn_mfma_f32_16x16x32_bf16(kf0, qf[qt][0], st[mt][qt], 0, 0, 0);
        st[mt][qt] = __builtin_amdgcn_mfma_f32_16x16x32_bf16(kf1, qf[qt][1], st[mt][qt], 0, 0, 0);
      }
    }

    // online softmax per q-subtile (log2 domain; scale folded into Q)
    float fac[2];
    unsigned pw[2][2][4];
#pragma unroll
    for (int qt = 0; qt < 2; ++qt) {
      float pm = mrow[qt];
#pragma unroll
      for (int mt = 0; mt < 4; ++mt)
#pragma unroll
        for (int r = 0; r < 4; ++r) pm = fmaxf(pm, st[mt][qt][r]);
      pm = fmaxf(pm, __shfl_xor(pm, 16));
      pm = fmaxf(pm, __shfl_xor(pm, 32));
      fac[qt] = exp2f(mrow[qt] - pm);
      mrow[qt] = pm;
      float ps = 0.f;
      float p[4][4];
#pragma unroll
      for (int mt = 0; mt < 4; ++mt)
#pragma unroll
        for (int r = 0; r < 4; ++r) {
          p[mt][r] = exp2f(st[mt][qt][r] - pm);
          ps += p[mt][r];
        }
      ps += __shfl_xor(ps, 16);
      ps += __shfl_xor(ps, 32);
      lrow[qt] = lrow[qt] * fac[qt] + ps;
      // pack P -> bf16 pairs (RNE via f2b bit-trick; do NOT use cvt_pk)
#pragma unroll
      for (int kk = 0; kk < 2; ++kk) {
        pw[qt][kk][0] = pack2(p[2 * kk][0], p[2 * kk][1]);
        pw[qt][kk][1] = pack2(p[2 * kk][2], p[2 * kk][3]);
        pw[qt][kk][2] = pack2(p[2 * kk + 1][0], p[2 * kk + 1][1]);
        pw[qt][kk][3] = pack2(p[2 * kk + 1][2], p[2 * kk + 1][3]);
      }
    }

    // rescale O accumulators (O rows are q = g*4+r; fac lives at lane q)
    float frow[2][4];
#pragma unroll
    for (int qt = 0; qt < 2; ++qt)
#pragma unroll
      for (int r = 0; r < 4; ++r) frow[qt][r] = __shfl(fac[qt], g * 4 + r);
#pragma unroll
    for (int nt = 0; nt < 4; ++nt)
#pragma unroll
      for (int qt = 0; qt < 2; ++qt) {
        acco[nt][qt][0] *= frow[qt][0]; acco[nt][qt][1] *= frow[qt][1];
        acco[nt][qt][2] *= frow[qt][2]; acco[nt][qt][3] *= frow[qt][3];
      }

    // O += P * V (V token-permuted so A-fragment = own packed P)
#pragma unroll
    for (int kk = 0; kk < 2; ++kk) {
#pragma unroll
      for (int nt = 0; nt < 4; ++nt) {
        int d = nt * 16 + col;
        unsigned off = vb + (unsigned)(d * 128) +
                       (unsigned)((kk * 64 + g * 16) ^ ((d & 7) << 4));
        bf16x8 vf = *(const bf16x8*)(lds + off);
#pragma unroll
        for (int qt = 0; qt < 2; ++qt) {
          union { unsigned u[4]; bf16x8 v; } pf;
          pf.u[0] = pw[qt][kk][0]; pf.u[1] = pw[qt][kk][1];
          pf.u[2] = pw[qt][kk][2]; pf.u[3] = pw[qt][kk][3];
          acco[nt][qt] = __builtin_amdgcn_mfma_f32_16x16x32_bf16(pf.v, vf, acco[nt][qt], 0, 0, 0);
        }
      }
    }
    __syncthreads();
  }

  // ---- merge 4 kv-partials per q-group in LDS (repurpose K/V regions) ----
  float* Om = (float*)lds;                    // [8 w][32 q][64 d]
  float* Ml = (float*)(lds + 65536);          // [8 w][32 q][2]
#pragma unroll
  for (int nt = 0; nt < 4; ++nt)
#pragma unroll
    for (int qt = 0; qt < 2; ++qt)
#pragma unroll
      for (int r = 0; r < 4; ++r)
        Om[w * 2048 + (qt * 16 + g * 4 + r) * 64 + nt * 16 + col] = acco[nt][qt][r];
  if (g == 0) {
#pragma unroll
    for (int qt = 0; qt < 2; ++qt) {
      Ml[(w * 32 + qt * 16 + col) * 2 + 0] = mrow[qt];
      Ml[(w * 32 + qt * 16 + col) * 2 + 1] = lrow[qt];
    }
  }
  __syncthreads();

  int qg2 = threadIdx.x >> 8, qq = (threadIdx.x >> 3) & 31, d0 = (threadIdx.x & 7) * 8;
  float mx = -1e30f;
#pragma unroll
  for (int k2 = 0; k2 < 4; ++k2)
    mx = fmaxf(mx, Ml[((qg2 * 4 + k2) * 32 + qq) * 2]);
  float den = 0.f, num[8] = {};
#pragma unroll
  for (int k2 = 0; k2 < 4; ++k2) {
    int wv = qg2 * 4 + k2;
    float wgt = exp2f(Ml[(wv * 32 + qq) * 2] - mx);
    den += wgt * Ml[(wv * 32 + qq) * 2 + 1];
#pragma unroll
    for (int i = 0; i < 8; ++i) num[i] += wgt * Om[wv * 2048 + qq * 64 + d0 + i];
  }
  float inv = 1.0f / den;
  union { unsigned short s[8]; bf16x8 v; } ov;
#pragma unroll
  for (int i = 0; i < 8; ++i) ov.s[i] = f2b(num[i] * inv);
  *(bf16x8*)(att + (qb + qg2 * 32 + qq) * DEMB + head * HD + d0) = ov.v;
}

// ---- output projection: att bf16 [n][256] @ wo + bo -> f32 out ----
__global__ __launch_bounds__(256) void outproj_kernel(
    const unsigned short* att, const unsigned short* wt_o, const float* bo,
    float* out) {
  int wave = threadIdx.x >> 6, lane = threadIdx.x & 63;
  int col = lane & 15, g = lane >> 4;
  int mbase = blockIdx.x * 64 + wave * 16;
  int nbase = blockIdx.y * 64;
  f32x4 acc[4] = {};
#pragma unroll
  for (int ks = 0; ks < 256; ks += 32) {
    bf16x8 af = *(const bf16x8*)(att + (mbase + col) * 256 + ks + g * 8);
#pragma unroll
    for (int nt = 0; nt < 4; ++nt) {
      bf16x8 bf_ = *(const bf16x8*)(wt_o + (nbase + nt * 16 + col) * 256 + ks + g * 8);
      acc[nt] = __builtin_amdgcn_mfma_f32_16x16x32_bf16(af, bf_, acc[nt], 0, 0, 0);
    }
  }
#pragma unroll
  for (int nt = 0; nt < 4; ++nt) {
    int c = nbase + nt * 16 + col;
    float b = bo[c];
#pragma unroll
    for (int r = 0; r < 4; ++r)
      out[(mbase + g * 4 + r) * 256 + c] = acc[nt][r] + b;
  }
}

extern "C" void kernel_launch(void* const* d_in, const int* in_sizes, int n_in,
                              void* d_out, int out_size, void* d_ws, size_t ws_size,
                              hipStream_t stream) {
  const float* q  = (const float*)d_in[0];
  const float* k  = (const float*)d_in[1];
  const float* v  = (const float*)d_in[2];
  const float* wq = (const float*)d_in[3];
  const float* bq = (const float*)d_in[4];
  const float* wk = (const float*)d_in[5];
  const float* bk = (const float*)d_in[6];
  const float* wv = (const float*)d_in[7];
  const float* bv = (const float*)d_in[8];
  const float* wo = (const float*)d_in[9];
  const float* bo = (const float*)d_in[10];
  float* out = (float*)d_out;

  char* ws = (char*)d_ws;
  float2* cs        = (float2*)ws;                       // 4096*32*8  = 1 MB
  unsigned short* wt = (unsigned short*)(ws + (1u << 20));  // 4*64K*2 = 512 KB
  unsigned short* qp = (unsigned short*)(ws + (1u << 20) + (512u << 10));  // 2 MB
  unsigned short* kp = qp + NHEAD * NTOK * HD;           // 2 MB
  unsigned short* vt = kp + NHEAD * NTOK * HD;           // 2 MB
  unsigned short* att = vt + NHEAD * NTOK * HD;          // 2 MB

  wtrans_kernel<<<1024, 256, 0, stream>>>(wq, wk, wv, wo, wt);
  cs_kernel<<<512, 256, 0, stream>>>(cs);
  qkvproj_kernel<<<dim3(64, 4, 3), 256, 0, stream>>>(q, k, v, wt, bq, bk, bv, cs,
                                                     qp, kp, vt);
  attn_kernel<<<256, 512, 0, stream>>>(qp, kp, vt, att);
  outproj_kernel<<<dim3(64, 4), 256, 0, stream>>>(att, wt + 3 * 65536, bo, out);
}